// Round 5
// baseline (158.551 us; speedup 1.0000x reference)
//
#include <hip/hip_runtime.h>

// SimpleCRFHead R10: lane-per-sequence layout. Each lane owns ALL 9 states
// of one sequence in registers; E (9x9 exp(tran)) lives in 81 wave-uniform
// VGPRs; per step: 9 ds_read (x) + 9 v_exp + 81 FMA (9 indep chains) +
// 9 mul -- no cross-lane DPP, no pad-group work. ~2x fewer issue slots
// per seq-step than quad-split and deeper ILP (R9 showed TLP scaling is
// a wash; attack instruction count + chains instead).
// 256 blocks x 64 threads (128 fwd + 128 bwd), 64 seqs/block.
// Staging: proven coalesced gl_lds4 + per-window vmcnt(0) double buffer.
// Math identical to R5/R9 (same exp-space recursion, once-per-window
// rescale, ce/emit/trn bookkeeping) -> absmax 0.0 preserved.

#define B_N 8192
#define L_N 256
#define SEQ_STRIDE 2304      // L_N * 9
#define HALF 128
#define SPB 6                // steps per x window
#define XW 54                // floats per seq per window
#define XSTRIDE 55           // odd -> conflict-free LDS banks (gcd(55,32)=1)
#define NBLK 22              // ceil(128/6)
#define PLS 129              // path LDS row stride ((129%32)=1 -> conflict-free)
#define SPW 64               // seqs per wave (one per lane)
#define NDIR_BLOCKS (B_N / SPW)   // 128 per direction

#define LOG2E 1.44269504088896340736f
#define LN2f  0.69314718055994530942f

#define WAITV0 asm volatile("s_waitcnt vmcnt(0)" ::: "memory")

__device__ __forceinline__ void gl_lds4(const void* g, void* l) {
  __builtin_amdgcn_global_load_lds(
      (const __attribute__((address_space(1))) void*)g,
      (__attribute__((address_space(3))) void*)l, 4, 0, 0);
}

__device__ __forceinline__ float fexp(float x) {
  return __builtin_amdgcn_exp2f(x * LOG2E);   // v_exp_f32 = 2^x
}

__global__ __launch_bounds__(64, 1) void crf_half(
    const float* __restrict__ xg, const int* __restrict__ path,
    const float* __restrict__ tran, const float* __restrict__ initv,
    float* __restrict__ ws)
{
  __shared__ float lx[2][SPW * XSTRIDE];  // 28160 B (double buffer)
  __shared__ int   pl[SPW * PLS];         // 33024 B
  __shared__ float ltran[81];             // ~61.5 KB total

  const int lane = threadIdx.x;           // = sequence slot (0..63)
  const bool fwd = (int)blockIdx.x < NDIR_BLOCKS;
  const int seq0 = (fwd ? blockIdx.x : blockIdx.x - NDIR_BLOCKS) * SPW;

  for (int i = lane; i < 81; i += 64) ltran[i] = tran[i];

  // ---- E matrix in registers (wave-uniform values, 81 VGPRs)
  // fwd: a'[i] = e_x[i] * sum_j exp(tran[j*9+i]) * a[j]
  // bwd: o'[i] = sum_j exp(tran[i*9+j]) * (e_x[j]*o[j])
  float E[9][9];
#pragma unroll
  for (int i = 0; i < 9; ++i)
#pragma unroll
    for (int j = 0; j < 9; ++j)
      E[i][j] = fexp(fwd ? tran[j * 9 + i] : tran[i * 9 + j]);

  float iv[9];
#pragma unroll
  for (int j = 0; j < 9; ++j) iv[j] = initv[j];   // uniform s_load

  float a[9];                 // all 9 states, lane-local
  float emit = 0.f, trn = 0.f;
  int ce = 0, pcur = 0;
  if (!fwd) {
#pragma unroll
    for (int j = 0; j < 9; ++j) a[j] = 1.f;
    pcur = path[(size_t)(seq0 + lane) * L_N + 255];   // p_255, per lane
  }
  asm volatile("" :: "v"(pcur));   // pin load + wait to prologue

  // ---- stage path rows (coalesced 64-wide, 2 per seq row)
  {
    const int t0 = fwd ? 0 : 127;
#pragma unroll 4
    for (int r = 0; r < SPW; ++r) {
      const int* g = path + (size_t)(seq0 + r) * L_N + t0 + lane;
      gl_lds4(g,      &pl[r * PLS]);
      gl_lds4(g + 64, &pl[r * PLS + 64]);
    }
  }
  // ---- stage x window 0
  if (lane < XW) {
    const int fb = fwd ? 0 : (SEQ_STRIDE - XW);
#pragma unroll 4
    for (int r = 0; r < SPW; ++r)
      gl_lds4(xg + (size_t)(seq0 + r) * SEQ_STRIDE + fb + lane,
              &lx[0][r * XSTRIDE]);
  }

  const int* plr = &pl[lane * PLS];

#pragma unroll 1
  for (int b = 0; b < NBLK; ++b) {
    WAITV0;                   // window b staged

    // prefetch window b+1 (waited one full window of compute later)
    if (b + 1 < NBLK && lane < XW) {
      const int fb = fwd ? (b + 1) * XW : (SEQ_STRIDE - XW * (b + 2));
      float* dst = &lx[(b + 1) & 1][0];
#pragma unroll 4
      for (int r = 0; r < SPW; ++r)
        gl_lds4(xg + (size_t)(seq0 + r) * SEQ_STRIDE + fb + lane,
                dst + r * XSTRIDE);
    }

    const float* lxr = &lx[b & 1][lane * XSTRIDE];

    if (fwd) {
#pragma unroll
      for (int kk = 0; kk < SPB; ++kk) {
        const int t = b * SPB + kk;
        if (t < HALF) {
          float xv[9], ee[9];
#pragma unroll
          for (int j = 0; j < 9; ++j) xv[j] = lxr[kk * 9 + j];
#pragma unroll
          for (int j = 0; j < 9; ++j) ee[j] = fexp(xv[j]);
          if (t == 0) {
#pragma unroll
            for (int j = 0; j < 9; ++j) a[j] = fexp(iv[j] + xv[j]);
            pcur = plr[0];
            emit += lxr[pcur];
          } else {
            if (kk == 0 && b > 0) {   // rescale once per window
              float m = a[0];
#pragma unroll
              for (int j = 1; j < 9; ++j) m = fmaxf(m, a[j]);
              const int ex = (int)((__float_as_uint(m) >> 23) & 0xffu) - 126;
              ce += ex;
              const float sc = __uint_as_float((unsigned)(127 - ex) << 23);
#pragma unroll
              for (int j = 0; j < 9; ++j) a[j] *= sc;
            }
            float outv[9];
#pragma unroll
            for (int i = 0; i < 9; ++i) {
              float acc = E[i][0] * a[0];
#pragma unroll
              for (int j = 1; j < 9; ++j) acc = fmaf(E[i][j], a[j], acc);
              outv[i] = acc;
            }
            const int p = plr[t];
            emit += lxr[kk * 9 + p];
            trn  += ltran[pcur * 9 + p];
            pcur = p;
#pragma unroll
            for (int i = 0; i < 9; ++i) a[i] = outv[i] * ee[i];
          }
        }
      }
    } else {
#pragma unroll
      for (int kk = 0; kk < SPB; ++kk) {
        const int t = 255 - b * SPB - kk;
        if (t >= HALF) {
          const int tt = SPB - 1 - kk;
          float xv[9], ee[9], wv[9];
#pragma unroll
          for (int j = 0; j < 9; ++j) xv[j] = lxr[tt * 9 + j];
#pragma unroll
          for (int j = 0; j < 9; ++j) ee[j] = fexp(xv[j]);
#pragma unroll
          for (int j = 0; j < 9; ++j) wv[j] = ee[j] * a[j];
          if (kk == 0 && b > 0) {
            float m = wv[0];
#pragma unroll
            for (int j = 1; j < 9; ++j) m = fmaxf(m, wv[j]);
            const int ex = (int)((__float_as_uint(m) >> 23) & 0xffu) - 126;
            ce += ex;
            const float sc = __uint_as_float((unsigned)(127 - ex) << 23);
#pragma unroll
            for (int j = 0; j < 9; ++j) wv[j] *= sc;
          }
          float outv[9];
#pragma unroll
          for (int i = 0; i < 9; ++i) {
            float acc = E[i][0] * wv[0];
#pragma unroll
            for (int j = 1; j < 9; ++j) acc = fmaf(E[i][j], wv[j], acc);
            outv[i] = acc;
          }
          // path score: emit for t (state pcur), tran pair (p_{t-1}, p_t)
          emit += lxr[tt * 9 + pcur];
          const int pm = plr[t - 128];
          trn += ltran[pm * 9 + pcur];
          pcur = pm;
#pragma unroll
          for (int i = 0; i < 9; ++i) a[i] = outv[i];
        }
      }
    }
  }

  // ---- write partials (field-major, lane-consecutive -> coalesced)
  const int sq = seq0 + lane;
  float* wp = ws + sq;
  if (fwd) {
#pragma unroll
    for (int i = 0; i < 9; ++i) wp[i * B_N] = a[i];
    wp[9 * B_N] = (float)ce;
    wp[10 * B_N] = emit + trn + initv[plr[0]];
  } else {
#pragma unroll
    for (int i = 0; i < 9; ++i) wp[(11 + i) * B_N] = a[i];
    wp[20 * B_N] = (float)ce;
    wp[21 * B_N] = emit + trn;
  }
}

__global__ __launch_bounds__(256) void crf_combine(
    const float* __restrict__ ws, float* __restrict__ out)
{
  const int s = blockIdx.x * 256 + threadIdx.x;
  float dot = 0.f;
#pragma unroll
  for (int i = 0; i < 9; ++i)
    dot = fmaf(ws[i * B_N + s], ws[(11 + i) * B_N + s], dot);
  const float score =
      (__builtin_amdgcn_logf(dot) + ws[9 * B_N + s] + ws[20 * B_N + s]) * LN2f;
  out[s] = score - (ws[10 * B_N + s] + ws[21 * B_N + s]);
}

extern "C" void kernel_launch(void* const* d_in, const int* in_sizes, int n_in,
                              void* d_out, int out_size, void* d_ws, size_t ws_size,
                              hipStream_t stream) {
  (void)in_sizes; (void)n_in; (void)out_size; (void)ws_size;
  const float* xg    = (const float*)d_in[0];
  const int*   path  = (const int*)d_in[1];
  const float* tran  = (const float*)d_in[2];
  const float* initv = (const float*)d_in[3];
  float* ws  = (float*)d_ws;    // 22*8192*4 = 721 KB
  float* out = (float*)d_out;

  crf_half<<<2 * NDIR_BLOCKS, 64, 0, stream>>>(xg, path, tran, initv, ws);
  crf_combine<<<B_N / 256, 256, 0, stream>>>(ws, out);
}

// Round 6
// 153.786 us; speedup vs baseline: 1.0310x; 1.0310x over previous
//
#include <hip/hip_runtime.h>

// SimpleCRFHead R11: lane-per-sequence with latency-hidden LDS schedule.
// Layout as R10 (each lane owns all 9 states of one seq; E=exp(tran) in 81
// wave-uniform VGPRs; 81 FMA + 9 exp per step). Change vs R10: all LDS
// reads are batched & issued long before first use --
//   x: whole 54-float window read to regs (xrA/xrB) at window top, one
//      lgkm wait per 27-batch instead of per-step stalls (bwd reads the
//      second half first since it consumes t descending);
//   path p: pre-read for window b+1 during window b (zero exposed wait);
//   emit/tran: issued at window top (addresses from pre-read p), consumed
//      at window end (R8's proven batched logic, verbatim).
// Math identical to R10 (passed, absmax 0.0). 256 blocks x 64 threads.

#define B_N 8192
#define L_N 256
#define SEQ_STRIDE 2304      // L_N * 9
#define HALF 128
#define SPB 6                // steps per x window
#define XW 54                // floats per seq per window
#define XSTRIDE 55           // odd -> conflict-free LDS banks (gcd(55,32)=1)
#define NBLK 22              // ceil(128/6)
#define PLS 129              // path LDS row stride (129%32=1 -> conflict-free)
#define SPW 64               // seqs per wave (one per lane)
#define NDIR_BLOCKS (B_N / SPW)   // 128 per direction

#define LOG2E 1.44269504088896340736f
#define LN2f  0.69314718055994530942f

#define WAITV0 asm volatile("s_waitcnt vmcnt(0)" ::: "memory")

__device__ __forceinline__ void gl_lds4(const void* g, void* l) {
  __builtin_amdgcn_global_load_lds(
      (const __attribute__((address_space(1))) void*)g,
      (__attribute__((address_space(3))) void*)l, 4, 0, 0);
}

__device__ __forceinline__ float fexp(float x) {
  return __builtin_amdgcn_exp2f(x * LOG2E);   // v_exp_f32 = 2^x
}

// ---- per-step bodies (KK, LT compile-time -> all reg indices static)
#define RESCALE9(V)                                                         \
  {                                                                         \
    float m = V[0];                                                         \
    _Pragma("unroll") for (int j = 1; j < 9; ++j) m = fmaxf(m, V[j]);       \
    const int ex = (int)((__float_as_uint(m) >> 23) & 0xffu) - 126;         \
    ce += ex;                                                               \
    const float sc = __uint_as_float((unsigned)(127 - ex) << 23);           \
    _Pragma("unroll") for (int j = 0; j < 9; ++j) V[j] *= sc;               \
  }

#define FWD_STEP(KK, ARR, LT)                                               \
  {                                                                         \
    const int t = tb + (KK);                                                \
    if (t < HALF) {                                                         \
      float xv[9], ee[9];                                                   \
      _Pragma("unroll") for (int j = 0; j < 9; ++j)                         \
          xv[j] = ARR[(LT) * 9 + j];                                        \
      _Pragma("unroll") for (int j = 0; j < 9; ++j) ee[j] = fexp(xv[j]);    \
      if (t == 0) {                                                         \
        _Pragma("unroll") for (int j = 0; j < 9; ++j)                       \
            a[j] = fexp(iv[j] + xv[j]);                                     \
      } else {                                                              \
        if ((KK) == 0 && b > 0) RESCALE9(a)                                 \
        float outv[9];                                                      \
        _Pragma("unroll") for (int i = 0; i < 9; ++i) {                     \
          float acc = E[i][0] * a[0];                                       \
          _Pragma("unroll") for (int j = 1; j < 9; ++j)                     \
              acc = fmaf(E[i][j], a[j], acc);                               \
          outv[i] = acc;                                                    \
        }                                                                   \
        _Pragma("unroll") for (int i = 0; i < 9; ++i)                       \
            a[i] = outv[i] * ee[i];                                         \
      }                                                                     \
    }                                                                       \
  }

#define BWD_STEP(KK, ARR, LT)                                               \
  {                                                                         \
    const int t = 255 - tb - (KK);                                          \
    if (t >= HALF) {                                                        \
      float xv[9], ee[9], wv[9];                                            \
      _Pragma("unroll") for (int j = 0; j < 9; ++j)                         \
          xv[j] = ARR[(LT) * 9 + j];                                        \
      _Pragma("unroll") for (int j = 0; j < 9; ++j) ee[j] = fexp(xv[j]);    \
      _Pragma("unroll") for (int j = 0; j < 9; ++j) wv[j] = ee[j] * a[j];   \
      if ((KK) == 0 && b > 0) RESCALE9(wv)                                  \
      float outv[9];                                                        \
      _Pragma("unroll") for (int i = 0; i < 9; ++i) {                       \
        float acc = E[i][0] * wv[0];                                        \
        _Pragma("unroll") for (int j = 1; j < 9; ++j)                       \
            acc = fmaf(E[i][j], wv[j], acc);                                \
        outv[i] = acc;                                                      \
      }                                                                     \
      _Pragma("unroll") for (int i = 0; i < 9; ++i) a[i] = outv[i];         \
    }                                                                       \
  }

__global__ __launch_bounds__(64, 1) void crf_half(
    const float* __restrict__ xg, const int* __restrict__ path,
    const float* __restrict__ tran, const float* __restrict__ initv,
    float* __restrict__ ws)
{
  __shared__ float lx[2][SPW * XSTRIDE];  // 28160 B (double buffer)
  __shared__ int   pl[SPW * PLS];         // 33024 B
  __shared__ float ltran[81];

  const int lane = threadIdx.x;           // = sequence slot (0..63)
  const bool fwd = (int)blockIdx.x < NDIR_BLOCKS;
  const int seq0 = (fwd ? blockIdx.x : blockIdx.x - NDIR_BLOCKS) * SPW;

  for (int i = lane; i < 81; i += 64) ltran[i] = tran[i];

  // E matrix in registers (wave-uniform, 81 VGPR)
  float E[9][9];
#pragma unroll
  for (int i = 0; i < 9; ++i)
#pragma unroll
    for (int j = 0; j < 9; ++j)
      E[i][j] = fexp(fwd ? tran[j * 9 + i] : tran[i * 9 + j]);

  float iv[9];
#pragma unroll
  for (int j = 0; j < 9; ++j) iv[j] = initv[j];

  float a[9];
  float emit = 0.f, trn = 0.f;
  int ce = 0, pcur = 0;
  if (!fwd) {
#pragma unroll
    for (int j = 0; j < 9; ++j) a[j] = 1.f;
    pcur = path[(size_t)(seq0 + lane) * L_N + 255];
  }
  asm volatile("" :: "v"(pcur));   // pin load + wait to prologue

  // ---- stage path rows + x window 0 (coalesced gl_lds)
  {
    const int t0 = fwd ? 0 : 127;
#pragma unroll 4
    for (int r = 0; r < SPW; ++r) {
      const int* g = path + (size_t)(seq0 + r) * L_N + t0 + lane;
      gl_lds4(g,      &pl[r * PLS]);
      gl_lds4(g + 64, &pl[r * PLS + 64]);
    }
  }
  if (lane < XW) {
    const int fb = fwd ? 0 : (SEQ_STRIDE - XW);
#pragma unroll 4
    for (int r = 0; r < SPW; ++r)
      gl_lds4(xg + (size_t)(seq0 + r) * SEQ_STRIDE + fb + lane,
              &lx[0][r * XSTRIDE]);
  }

  const int* plr = &pl[lane * PLS];
  WAITV0;                           // path + window 0 staged

  // pre-read p for window 0
  int pc6[6];
  if (fwd) {
#pragma unroll
    for (int kk = 0; kk < 6; ++kk) pc6[kk] = plr[kk];
  } else {
#pragma unroll
    for (int kk = 0; kk < 6; ++kk) pc6[kk] = plr[127 - kk];
  }

#pragma unroll 1
  for (int b = 0; b < NBLK; ++b) {
    const int tb = b * SPB;
    if (b) WAITV0;                  // window b staged

    // prefetch window b+1 (VMEM; waited one full window later)
    if (b + 1 < NBLK && lane < XW) {
      const int fb = fwd ? (b + 1) * XW : (SEQ_STRIDE - XW * (b + 2));
      float* dst = &lx[(b + 1) & 1][0];
#pragma unroll 4
      for (int r = 0; r < SPW; ++r)
        gl_lds4(xg + (size_t)(seq0 + r) * SEQ_STRIDE + fb + lane,
                dst + r * XSTRIDE);
    }

    const float* lxr = &lx[b & 1][lane * XSTRIDE];

    // ---- x window -> registers (first-consumed half read first)
    float xrA[27], xrB[27];
    if (fwd) {
#pragma unroll
      for (int j = 0; j < 27; ++j) xrA[j] = lxr[j];
#pragma unroll
      for (int j = 0; j < 27; ++j) xrB[j] = lxr[27 + j];
    } else {
#pragma unroll
      for (int j = 0; j < 27; ++j) xrB[j] = lxr[27 + j];
#pragma unroll
      for (int j = 0; j < 27; ++j) xrA[j] = lxr[j];
    }

    // ---- emit/tran reads (addresses from pre-read p; consumed at end)
    float em[6], tr[6];
    if (fwd) {
#pragma unroll
      for (int kk = 0; kk < 6; ++kk) {
        em[kk] = lxr[kk * 9 + pc6[kk]];
        const int pp = kk ? pc6[kk - 1] : pcur;
        tr[kk] = ltran[pp * 9 + pc6[kk]];
      }
    } else {
#pragma unroll
      for (int kk = 0; kk < 6; ++kk) {
        const int pc = kk ? pc6[kk - 1] : pcur;
        em[kk] = lxr[(5 - kk) * 9 + pc];
        tr[kk] = ltran[pc6[kk] * 9 + pc];
      }
    }

    // ---- pre-read p for window b+1 (clamped; wait fully amortized)
    int pn6[6];
    {
      const int tbn = tb + SPB;
      if (fwd) {
#pragma unroll
        for (int kk = 0; kk < 6; ++kk) {
          int t = tbn + kk; if (t > HALF - 1) t = HALF - 1;
          pn6[kk] = plr[t];
        }
      } else {
#pragma unroll
        for (int kk = 0; kk < 6; ++kk) {
          int idx = 127 - tbn - kk; if (idx < 0) idx = 0;
          pn6[kk] = plr[idx];
        }
      }
    }

    // ---- recursion (register-only; guards uniform in t)
    if (fwd) {
      FWD_STEP(0, xrA, 0)
      FWD_STEP(1, xrA, 1)
      FWD_STEP(2, xrA, 2)
      FWD_STEP(3, xrB, 0)
      FWD_STEP(4, xrB, 1)
      FWD_STEP(5, xrB, 2)
#pragma unroll
      for (int kk = 0; kk < 6; ++kk) {
        const int t = tb + kk;
        if (t < HALF) {
          emit += em[kk];
          if (kk > 0 || b > 0) trn += tr[kk];   // t==0 has no transition
        }
      }
    } else {
      BWD_STEP(0, xrB, 2)
      BWD_STEP(1, xrB, 1)
      BWD_STEP(2, xrB, 0)
      BWD_STEP(3, xrA, 2)
      BWD_STEP(4, xrA, 1)
      BWD_STEP(5, xrA, 0)
#pragma unroll
      for (int kk = 0; kk < 6; ++kk) {
        if (255 - tb - kk >= HALF) { emit += em[kk]; trn += tr[kk]; }
      }
    }

    pcur = pc6[5];
#pragma unroll
    for (int kk = 0; kk < 6; ++kk) pc6[kk] = pn6[kk];
  }

  // ---- write partials (field-major, lane-consecutive -> coalesced)
  const int sq = seq0 + lane;
  float* wp = ws + sq;
  if (fwd) {
#pragma unroll
    for (int i = 0; i < 9; ++i) wp[i * B_N] = a[i];
    wp[9 * B_N] = (float)ce;
    wp[10 * B_N] = emit + trn + initv[plr[0]];
  } else {
#pragma unroll
    for (int i = 0; i < 9; ++i) wp[(11 + i) * B_N] = a[i];
    wp[20 * B_N] = (float)ce;
    wp[21 * B_N] = emit + trn;
  }
}

__global__ __launch_bounds__(256) void crf_combine(
    const float* __restrict__ ws, float* __restrict__ out)
{
  const int s = blockIdx.x * 256 + threadIdx.x;
  float dot = 0.f;
#pragma unroll
  for (int i = 0; i < 9; ++i)
    dot = fmaf(ws[i * B_N + s], ws[(11 + i) * B_N + s], dot);
  const float score =
      (__builtin_amdgcn_logf(dot) + ws[9 * B_N + s] + ws[20 * B_N + s]) * LN2f;
  out[s] = score - (ws[10 * B_N + s] + ws[21 * B_N + s]);
}

extern "C" void kernel_launch(void* const* d_in, const int* in_sizes, int n_in,
                              void* d_out, int out_size, void* d_ws, size_t ws_size,
                              hipStream_t stream) {
  (void)in_sizes; (void)n_in; (void)out_size; (void)ws_size;
  const float* xg    = (const float*)d_in[0];
  const int*   path  = (const int*)d_in[1];
  const float* tran  = (const float*)d_in[2];
  const float* initv = (const float*)d_in[3];
  float* ws  = (float*)d_ws;    // 22*8192*4 = 721 KB
  float* out = (float*)d_out;

  crf_half<<<2 * NDIR_BLOCKS, 64, 0, stream>>>(xg, path, tran, initv, ws);
  crf_combine<<<B_N / 256, 256, 0, stream>>>(ws, out);
}

// Round 7
// 135.072 us; speedup vs baseline: 1.1738x; 1.1385x over previous
//
#include <hip/hip_runtime.h>

// SimpleCRFHead R12: R9 (split quad-split, SPW=8, 2 waves/SIMD, proven
// 48us) + R8's batched path-score pipeline (proven correct in fused):
//   - p indices for window b+1 pre-read during window b (no exposed wait)
//   - emit/tran LDS reads issued at window top from pre-read p, consumed
//     at window end -> per-step bodies are register-only
//   - iv hoisted & pinned to prologue (no global load sinks into loop)
// Removes the ~240cy/step dependent LDS chain (p -> emit/tran) that R9
// left in the split structure. Everything else identical to R9.

#define B_N 8192
#define L_N 256
#define SEQ_STRIDE 2304      // L_N * 9
#define HALF 128
#define SPB 6                // steps per x window
#define XW 54                // floats per seq per window
#define XSTRIDE 55           // odd -> conflict-free LDS banks
#define NBLK 22              // ceil(128/6)
#define PLS 129              // path LDS row stride
#define SPW 8                // seqs per wave
#define NDIR_BLOCKS (B_N / SPW)   // 1024 per direction

#define LOG2E 1.44269504088896340736f
#define LN2f  0.69314718055994530942f

// quad_perm rotate-left-by-r: lane c receives quad-lane (c+r)&3
#define QP1 57    // perm(1,2,3,0)
#define QP2 78    // perm(2,3,0,1)
#define QP3 147   // perm(3,0,1,2)
#define QROT(src, CTRL) \
  __int_as_float(__builtin_amdgcn_mov_dpp(__float_as_int(src), CTRL, 0xf, 0xf, 0))

#define WAITV0 asm volatile("s_waitcnt vmcnt(0)" ::: "memory")

__device__ __forceinline__ void gl_lds4(const void* g, void* l) {
  __builtin_amdgcn_global_load_lds(
      (const __attribute__((address_space(1))) void*)g,
      (__attribute__((address_space(3))) void*)l, 4, 0, 0);
}

__device__ __forceinline__ float fexp(float x) {
  return __builtin_amdgcn_exp2f(x * LOG2E);   // v_exp_f32 = 2^x
}

__global__ __launch_bounds__(64, 2) void crf_half(
    const float* __restrict__ xg, const int* __restrict__ path,
    const float* __restrict__ tran, const float* __restrict__ initv,
    float* __restrict__ ws)
{
  __shared__ float lx[2][SPW * XSTRIDE];  // 3520 B
  __shared__ int   pl[SPW * PLS];         // 4128 B
  __shared__ int   pl255[SPW];
  __shared__ float ltran[81];             // ~8.1 KB total -> 8+ blocks/CU

  const int lane = threadIdx.x;
  const int c = lane & 3;                 // quad slot (state group)
  const int q = lane >> 2;                // seq slot within wave
  const int qc = (q < SPW) ? q : (SPW - 1);   // clamp inert upper quads
  const bool fwd = (int)blockIdx.x < NDIR_BLOCKS;
  const int seq0 = (fwd ? blockIdx.x : blockIdx.x - NDIR_BLOCKS) * SPW;

  for (int i = lane; i < 81; i += 64) ltran[i] = tran[i];

  // ---- stage path rows (gl_lds, coalesced 64-wide)
  {
    const int t0 = fwd ? 0 : 127;
#pragma unroll
    for (int r = 0; r < SPW; ++r) {
      const int* g = path + (size_t)(seq0 + r) * L_N + t0 + lane;
      gl_lds4(g,      &pl[r * PLS]);
      gl_lds4(g + 64, &pl[r * PLS + 64]);
    }
  }
  if (!fwd && lane < SPW)
    pl255[lane] = path[(size_t)(seq0 + lane) * L_N + 255];

  // ---- stage x window 0
  if (lane < XW) {
    const int fb = fwd ? 0 : (SEQ_STRIDE - XW);
#pragma unroll
    for (int r = 0; r < SPW; ++r)
      gl_lds4(xg + (size_t)(seq0 + r) * SEQ_STRIDE + fb + lane,
              &lx[0][r * XSTRIDE]);
  }

  // ---- rotation-ordered transition coefficients (prologue only)
  float Erot[4][3][3];
#pragma unroll
  for (int r = 0; r < 4; ++r)
#pragma unroll
    for (int k = 0; k < 3; ++k)
#pragma unroll
      for (int i = 0; i < 3; ++i) {
        const int ig = 3 * c + i;
        const int jg = 3 * ((c + r) & 3) + k;
        float v = 0.f;
        if (ig < 9 && jg < 9)
          v = fexp(fwd ? tran[jg * 9 + ig] : tran[ig * 9 + jg]);
        Erot[r][k][i] = v;
      }

  float iv[3];
#pragma unroll
  for (int k = 0; k < 3; ++k) {
    iv[k] = (fwd && c < 3) ? initv[3 * c + k] : 0.f;
    asm volatile("" :: "v"(iv[k]));       // pin materialization to prologue
  }

  float o[3];                 // own 3 states (c==3: always 0)
  float emit = 0.f, trn = 0.f;
  int ce = 0, pcur = 0;

  if (!fwd) {
#pragma unroll
    for (int k = 0; k < 3; ++k) o[k] = (c < 3) ? 1.f : 0.f;
    pcur = pl255[qc];         // p_255
  }

  const int myoff = (c == 3) ? 0 : 3 * c;
  const int* plr = &pl[qc * PLS];

  WAITV0;                     // path rows + window 0 staged

  // ---- pre-read p for window 0 (pc6[kk]: fwd p_t, bwd p_{t-1})
  int pc6[SPB];
  if (fwd) {
#pragma unroll
    for (int kk = 0; kk < SPB; ++kk) pc6[kk] = plr[kk];
  } else {
#pragma unroll
    for (int kk = 0; kk < SPB; ++kk) pc6[kk] = plr[127 - kk];
  }

#pragma unroll 1
  for (int b = 0; b < NBLK; ++b) {
    const int tb = b * SPB;
    if (b) WAITV0;            // window b staged

    // prefetch window b+1 (waited one full window of compute later)
    if (b + 1 < NBLK && lane < XW) {
      const int fb = fwd ? (b + 1) * XW : (SEQ_STRIDE - XW * (b + 2));
      float* dst = &lx[(b + 1) & 1][0];
#pragma unroll
      for (int r = 0; r < SPW; ++r)
        gl_lds4(xg + (size_t)(seq0 + r) * SEQ_STRIDE + fb + lane,
                dst + r * XSTRIDE);
    }

    const float* lxq = &lx[b & 1][qc * XSTRIDE];

    // ---- own-state exps for the whole window (batched LDS reads)
    float e[SPB * 3];
#pragma unroll
    for (int tt = 0; tt < SPB; ++tt)
#pragma unroll
      for (int k = 0; k < 3; ++k)
        e[tt * 3 + k] = fexp(lxq[tt * 9 + myoff + k]);

    // ---- batched emit/tran reads (addresses from pre-read p)
    float em[SPB], tr[SPB];
    if (fwd) {
#pragma unroll
      for (int kk = 0; kk < SPB; ++kk) {
        em[kk] = lxq[kk * 9 + pc6[kk]];
        const int pp = kk ? pc6[kk - 1] : pcur;
        tr[kk] = ltran[pp * 9 + pc6[kk]];
      }
    } else {
#pragma unroll
      for (int kk = 0; kk < SPB; ++kk) {
        const int pc = kk ? pc6[kk - 1] : pcur;
        em[kk] = lxq[(SPB - 1 - kk) * 9 + pc];
        tr[kk] = ltran[pc6[kk] * 9 + pc];
      }
    }

    // ---- pre-read p for window b+1 (clamped; wait amortized over window)
    int pn6[SPB];
    {
      const int tbn = tb + SPB;
      if (fwd) {
#pragma unroll
        for (int kk = 0; kk < SPB; ++kk) {
          int t = tbn + kk; if (t > HALF - 1) t = HALF - 1;
          pn6[kk] = plr[t];
        }
      } else {
#pragma unroll
        for (int kk = 0; kk < SPB; ++kk) {
          int idx = 127 - tbn - kk; if (idx < 0) idx = 0;
          pn6[kk] = plr[idx];
        }
      }
    }

    // ---- recursion (register-only per step)
    if (fwd) {
#pragma unroll
      for (int kk = 0; kk < SPB; ++kk) {
        const int t = tb + kk;
        if (t < HALF) {
          if (t == 0) {
#pragma unroll
            for (int k = 0; k < 3; ++k)
              o[k] = (c < 3) ? fexp(iv[k] + lxq[myoff + k]) : 0.f;
          } else {
            float g[4][3];
#pragma unroll
            for (int k = 0; k < 3; ++k) {
              g[0][k] = o[k];
              g[1][k] = QROT(o[k], QP1);
              g[2][k] = QROT(o[k], QP2);
              g[3][k] = QROT(o[k], QP3);
            }
            if (kk == 0 && b > 0) {   // rescale once per window
              float m = g[0][0];
#pragma unroll
              for (int r = 0; r < 4; ++r)
#pragma unroll
                for (int k = 0; k < 3; ++k) m = fmaxf(m, g[r][k]);
              const int ex = (int)((__float_as_uint(m) >> 23) & 0xffu) - 126;
              ce += ex;
              const float sc = __uint_as_float((unsigned)(127 - ex) << 23);
#pragma unroll
              for (int r = 0; r < 4; ++r)
#pragma unroll
                for (int k = 0; k < 3; ++k) g[r][k] *= sc;
            }
            float out[3];
#pragma unroll
            for (int i = 0; i < 3; ++i) {
              float a = Erot[0][0][i] * g[0][0];
#pragma unroll
              for (int r = 0; r < 4; ++r)
#pragma unroll
                for (int k = 0; k < 3; ++k)
                  if (r + k > 0) a = fmaf(Erot[r][k][i], g[r][k], a);
              out[i] = a;
            }
#pragma unroll
            for (int i = 0; i < 3; ++i) o[i] = out[i] * e[kk * 3 + i];
          }
        }
      }
      // accumulate path score (uniform guards)
#pragma unroll
      for (int kk = 0; kk < SPB; ++kk) {
        const int t = tb + kk;
        if (t < HALF) {
          emit += em[kk];
          if (kk > 0 || b > 0) trn += tr[kk];   // t==0 has no transition
        }
      }
    } else {
#pragma unroll
      for (int kk = 0; kk < SPB; ++kk) {
        const int t = 255 - tb - kk;
        if (t >= HALF) {
          const int tt = SPB - 1 - kk;
          float w[3];
#pragma unroll
          for (int k = 0; k < 3; ++k) w[k] = e[tt * 3 + k] * o[k];
          float g[4][3];
#pragma unroll
          for (int k = 0; k < 3; ++k) {
            g[0][k] = w[k];
            g[1][k] = QROT(w[k], QP1);
            g[2][k] = QROT(w[k], QP2);
            g[3][k] = QROT(w[k], QP3);
          }
          if (kk == 0 && b > 0) {
            float m = g[0][0];
#pragma unroll
            for (int r = 0; r < 4; ++r)
#pragma unroll
              for (int k = 0; k < 3; ++k) m = fmaxf(m, g[r][k]);
            const int ex = (int)((__float_as_uint(m) >> 23) & 0xffu) - 126;
            ce += ex;
            const float sc = __uint_as_float((unsigned)(127 - ex) << 23);
#pragma unroll
            for (int r = 0; r < 4; ++r)
#pragma unroll
              for (int k = 0; k < 3; ++k) g[r][k] *= sc;
          }
#pragma unroll
          for (int i = 0; i < 3; ++i) {
            float a = Erot[0][0][i] * g[0][0];
#pragma unroll
            for (int r = 0; r < 4; ++r)
#pragma unroll
              for (int k = 0; k < 3; ++k)
                if (r + k > 0) a = fmaf(Erot[r][k][i], g[r][k], a);
            o[i] = a;
          }
        }
      }
#pragma unroll
      for (int kk = 0; kk < SPB; ++kk) {
        if (255 - tb - kk >= HALF) { emit += em[kk]; trn += tr[kk]; }
      }
    }

    pcur = pc6[SPB - 1];
#pragma unroll
    for (int kk = 0; kk < SPB; ++kk) pc6[kk] = pn6[kk];
  }

  // ---- write partials (field-major); inert upper quads store nothing
  if (q < SPW) {
    const int sq = seq0 + q;
    float* wp = ws + sq;
    if (fwd) {
      if (c < 3) {
#pragma unroll
        for (int k = 0; k < 3; ++k) wp[(3 * c + k) * B_N] = o[k];
      } else {
        wp[9 * B_N] = (float)ce;
        wp[10 * B_N] = emit + trn + initv[plr[0]];
      }
    } else {
      if (c < 3) {
#pragma unroll
        for (int k = 0; k < 3; ++k) wp[(11 + 3 * c + k) * B_N] = o[k];
      } else {
        wp[20 * B_N] = (float)ce;
        wp[21 * B_N] = emit + trn;
      }
    }
  }
}

__global__ __launch_bounds__(256) void crf_combine(
    const float* __restrict__ ws, float* __restrict__ out)
{
  const int s = blockIdx.x * 256 + threadIdx.x;
  float dot = 0.f;
#pragma unroll
  for (int i = 0; i < 9; ++i)
    dot = fmaf(ws[i * B_N + s], ws[(11 + i) * B_N + s], dot);
  const float score =
      (__builtin_amdgcn_logf(dot) + ws[9 * B_N + s] + ws[20 * B_N + s]) * LN2f;
  out[s] = score - (ws[10 * B_N + s] + ws[21 * B_N + s]);
}

extern "C" void kernel_launch(void* const* d_in, const int* in_sizes, int n_in,
                              void* d_out, int out_size, void* d_ws, size_t ws_size,
                              hipStream_t stream) {
  (void)in_sizes; (void)n_in; (void)out_size; (void)ws_size;
  const float* xg    = (const float*)d_in[0];
  const int*   path  = (const int*)d_in[1];
  const float* tran  = (const float*)d_in[2];
  const float* initv = (const float*)d_in[3];
  float* ws  = (float*)d_ws;    // 22*8192*4 = 721 KB
  float* out = (float*)d_out;

  crf_half<<<2 * NDIR_BLOCKS, 64, 0, stream>>>(xg, path, tran, initv, ws);
  crf_combine<<<B_N / 256, 256, 0, stream>>>(ws, out);
}

// Round 8
// 126.485 us; speedup vs baseline: 1.2535x; 1.0679x over previous
//
#include <hip/hip_runtime.h>

// SimpleCRFHead R13: full-wave quad-split (R5 grid: SPW=16, 1024 blocks,
// 1 wave/SIMD, 100% lane efficiency) + R12's batched path-score pipeline
// (p pre-read one window ahead; em/tr batched at window top) + loop
// splitting: window 0 (t==0 special) / windows 1..20 branch-free (all
// guards compile-time, rescale folded at kk==0) / 2-step tail (t=126,127).
// Straight-line register-only step bodies let the scheduler overlap
// successive steps' DPP/FMA chains. Math identical to R5/R12 (absmax 0.0).

#define B_N 8192
#define L_N 256
#define SEQ_STRIDE 2304      // L_N * 9
#define HALF 128
#define SPB 6                // steps per x window
#define XW 54                // floats per seq per window
#define XSTRIDE 55           // odd -> conflict-free LDS banks
#define NBLK 22              // 21 full windows + 2-step tail (126+2=128)
#define PLS 129              // path LDS row stride
#define SPW 16               // seqs per wave (full wave: 16 quads)
#define NDIR_BLOCKS (B_N / SPW)   // 512 per direction

#define LOG2E 1.44269504088896340736f
#define LN2f  0.69314718055994530942f

// quad_perm rotate-left-by-r: lane c receives quad-lane (c+r)&3
#define QP1 57    // perm(1,2,3,0)
#define QP2 78    // perm(2,3,0,1)
#define QP3 147   // perm(3,0,1,2)
#define QROT(src, CTRL) \
  __int_as_float(__builtin_amdgcn_mov_dpp(__float_as_int(src), CTRL, 0xf, 0xf, 0))

#define WAITV0 asm volatile("s_waitcnt vmcnt(0)" ::: "memory")

__device__ __forceinline__ void gl_lds4(const void* g, void* l) {
  __builtin_amdgcn_global_load_lds(
      (const __attribute__((address_space(1))) void*)g,
      (__attribute__((address_space(3))) void*)l, 4, 0, 0);
}

__device__ __forceinline__ float fexp(float x) {
  return __builtin_amdgcn_exp2f(x * LOG2E);   // v_exp_f32 = 2^x
}

// ---- straight-line step bodies (KK, DO_RESC compile-time) ----
#define FWD_STEP_BODY(KK, DO_RESC)                                          \
  do {                                                                      \
    float g[4][3];                                                          \
    _Pragma("unroll") for (int k = 0; k < 3; ++k) {                         \
      g[0][k] = o[k];                                                       \
      g[1][k] = QROT(o[k], QP1);                                            \
      g[2][k] = QROT(o[k], QP2);                                            \
      g[3][k] = QROT(o[k], QP3);                                            \
    }                                                                       \
    if (DO_RESC) {                                                          \
      float m = g[0][0];                                                    \
      _Pragma("unroll") for (int r = 0; r < 4; ++r)                         \
        _Pragma("unroll") for (int k = 0; k < 3; ++k)                       \
          m = fmaxf(m, g[r][k]);                                            \
      const int ex = (int)((__float_as_uint(m) >> 23) & 0xffu) - 126;       \
      ce += ex;                                                             \
      const float sc = __uint_as_float((unsigned)(127 - ex) << 23);         \
      _Pragma("unroll") for (int r = 0; r < 4; ++r)                         \
        _Pragma("unroll") for (int k = 0; k < 3; ++k)                       \
          g[r][k] *= sc;                                                    \
    }                                                                       \
    float out3[3];                                                          \
    _Pragma("unroll") for (int i = 0; i < 3; ++i) {                         \
      float a = Erot[0][0][i] * g[0][0];                                    \
      _Pragma("unroll") for (int r = 0; r < 4; ++r)                         \
        _Pragma("unroll") for (int k = 0; k < 3; ++k)                       \
          if (r + k > 0) a = fmaf(Erot[r][k][i], g[r][k], a);               \
      out3[i] = a;                                                          \
    }                                                                       \
    _Pragma("unroll") for (int i = 0; i < 3; ++i)                           \
      o[i] = out3[i] * e[(KK) * 3 + i];                                     \
  } while (0)

#define BWD_STEP_BODY(KK, DO_RESC)                                          \
  do {                                                                      \
    const int tt_ = 5 - (KK);                                               \
    float wv[3];                                                            \
    _Pragma("unroll") for (int k = 0; k < 3; ++k)                           \
      wv[k] = e[tt_ * 3 + k] * o[k];                                        \
    float g[4][3];                                                          \
    _Pragma("unroll") for (int k = 0; k < 3; ++k) {                         \
      g[0][k] = wv[k];                                                      \
      g[1][k] = QROT(wv[k], QP1);                                           \
      g[2][k] = QROT(wv[k], QP2);                                           \
      g[3][k] = QROT(wv[k], QP3);                                           \
    }                                                                       \
    if (DO_RESC) {                                                          \
      float m = g[0][0];                                                    \
      _Pragma("unroll") for (int r = 0; r < 4; ++r)                         \
        _Pragma("unroll") for (int k = 0; k < 3; ++k)                       \
          m = fmaxf(m, g[r][k]);                                            \
      const int ex = (int)((__float_as_uint(m) >> 23) & 0xffu) - 126;       \
      ce += ex;                                                             \
      const float sc = __uint_as_float((unsigned)(127 - ex) << 23);         \
      _Pragma("unroll") for (int r = 0; r < 4; ++r)                         \
        _Pragma("unroll") for (int k = 0; k < 3; ++k)                       \
          g[r][k] *= sc;                                                    \
    }                                                                       \
    float out3[3];                                                          \
    _Pragma("unroll") for (int i = 0; i < 3; ++i) {                         \
      float a = Erot[0][0][i] * g[0][0];                                    \
      _Pragma("unroll") for (int r = 0; r < 4; ++r)                         \
        _Pragma("unroll") for (int k = 0; k < 3; ++k)                       \
          if (r + k > 0) a = fmaf(Erot[r][k][i], g[r][k], a);               \
      out3[i] = a;                                                          \
    }                                                                       \
    _Pragma("unroll") for (int i = 0; i < 3; ++i) o[i] = out3[i];           \
  } while (0)

#define PREFETCH_WIN(NB)                                                    \
  if (lane < XW) {                                                          \
    const int fb = fwd ? (NB) * XW : (SEQ_STRIDE - XW * ((NB) + 1));        \
    float* dst = &lx[(NB) & 1][0];                                          \
    _Pragma("unroll") for (int r = 0; r < SPW; ++r)                         \
      gl_lds4(xg + (size_t)(seq0 + r) * SEQ_STRIDE + fb + lane,             \
              dst + r * XSTRIDE);                                           \
  }

#define EBATCH(T0, T1)                                                      \
  _Pragma("unroll") for (int tt = (T0); tt <= (T1); ++tt)                   \
    _Pragma("unroll") for (int k = 0; k < 3; ++k)                           \
      e[tt * 3 + k] = fexp(lxq[tt * 9 + myoff + k]);

#define EMTR_FWD(N)                                                         \
  _Pragma("unroll") for (int kk = 0; kk < (N); ++kk) {                      \
    em[kk] = lxq[kk * 9 + pc6[kk]];                                         \
    const int pp = kk ? pc6[kk - 1] : pcur;                                 \
    tr[kk] = ltran[pp * 9 + pc6[kk]];                                       \
  }

#define EMTR_BWD(N)                                                         \
  _Pragma("unroll") for (int kk = 0; kk < (N); ++kk) {                      \
    const int pc = kk ? pc6[kk - 1] : pcur;                                 \
    em[kk] = lxq[(5 - kk) * 9 + pc];                                        \
    tr[kk] = ltran[pc6[kk] * 9 + pc];                                       \
  }

#define PREREAD_PN(TBN)                                                     \
  if (fwd) {                                                                \
    _Pragma("unroll") for (int kk = 0; kk < SPB; ++kk) {                    \
      int t = (TBN) + kk; if (t > HALF - 1) t = HALF - 1;                   \
      pn6[kk] = plr[t];                                                     \
    }                                                                       \
  } else {                                                                  \
    _Pragma("unroll") for (int kk = 0; kk < SPB; ++kk) {                    \
      int idx = 127 - (TBN) - kk; if (idx < 0) idx = 0;                     \
      pn6[kk] = plr[idx];                                                   \
    }                                                                       \
  }

__global__ __launch_bounds__(64, 1) void crf_half(
    const float* __restrict__ xg, const int* __restrict__ path,
    const float* __restrict__ tran, const float* __restrict__ initv,
    float* __restrict__ ws)
{
  __shared__ float lx[2][SPW * XSTRIDE];  // 7040 B
  __shared__ int   pl[SPW * PLS];         // 8256 B
  __shared__ int   pl255[SPW];
  __shared__ float ltran[81];             // ~15.7 KB -> 4 blocks/CU

  const int lane = threadIdx.x;
  const int c = lane & 3;                 // quad slot (state group)
  const int q = lane >> 2;                // seq slot (0..15, all active)
  const bool fwd = (int)blockIdx.x < NDIR_BLOCKS;
  const int seq0 = (fwd ? blockIdx.x : blockIdx.x - NDIR_BLOCKS) * SPW;

  for (int i = lane; i < 81; i += 64) ltran[i] = tran[i];

  // ---- stage path rows + x window 0 (coalesced gl_lds)
  {
    const int t0 = fwd ? 0 : 127;
#pragma unroll
    for (int r = 0; r < SPW; ++r) {
      const int* g = path + (size_t)(seq0 + r) * L_N + t0 + lane;
      gl_lds4(g,      &pl[r * PLS]);
      gl_lds4(g + 64, &pl[r * PLS + 64]);
    }
  }
  if (!fwd && lane < SPW)
    pl255[lane] = path[(size_t)(seq0 + lane) * L_N + 255];
  if (lane < XW) {
    const int fb = fwd ? 0 : (SEQ_STRIDE - XW);
#pragma unroll
    for (int r = 0; r < SPW; ++r)
      gl_lds4(xg + (size_t)(seq0 + r) * SEQ_STRIDE + fb + lane,
              &lx[0][r * XSTRIDE]);
  }

  // ---- rotation-ordered transition coefficients (prologue only)
  float Erot[4][3][3];
#pragma unroll
  for (int r = 0; r < 4; ++r)
#pragma unroll
    for (int k = 0; k < 3; ++k)
#pragma unroll
      for (int i = 0; i < 3; ++i) {
        const int ig = 3 * c + i;
        const int jg = 3 * ((c + r) & 3) + k;
        float v = 0.f;
        if (ig < 9 && jg < 9)
          v = fexp(fwd ? tran[jg * 9 + ig] : tran[ig * 9 + jg]);
        Erot[r][k][i] = v;
      }

  float iv[3];
#pragma unroll
  for (int k = 0; k < 3; ++k) {
    iv[k] = (fwd && c < 3) ? initv[3 * c + k] : 0.f;
    asm volatile("" :: "v"(iv[k]));       // pin materialization to prologue
  }

  float o[3];
  float emit = 0.f, trn = 0.f;
  int ce = 0, pcur = 0;
  if (!fwd) {
#pragma unroll
    for (int k = 0; k < 3; ++k) o[k] = (c < 3) ? 1.f : 0.f;
  }

  const int myoff = (c == 3) ? 0 : 3 * c;
  const int* plr = &pl[q * PLS];

  WAITV0;                     // path rows + window 0 staged
  if (!fwd) pcur = pl255[q];  // p_255 (LDS, same-wave producer)

  int pc6[SPB];
  if (fwd) {
#pragma unroll
    for (int kk = 0; kk < SPB; ++kk) pc6[kk] = plr[kk];
  } else {
#pragma unroll
    for (int kk = 0; kk < SPB; ++kk) pc6[kk] = plr[127 - kk];
  }

  // ================= window 0 (fwd: t==0 special) =================
  {
    PREFETCH_WIN(1)
    const float* lxq = &lx[0][q * XSTRIDE];
    float e[SPB * 3];
    EBATCH(0, 5)
    float em[SPB], tr[SPB];
    int pn6[SPB];
    if (fwd) { EMTR_FWD(6) } else { EMTR_BWD(6) }
    PREREAD_PN(SPB)
    if (fwd) {
#pragma unroll
      for (int k = 0; k < 3; ++k)
        o[k] = (c < 3) ? fexp(iv[k] + lxq[myoff + k]) : 0.f;
      FWD_STEP_BODY(1, false);
      FWD_STEP_BODY(2, false);
      FWD_STEP_BODY(3, false);
      FWD_STEP_BODY(4, false);
      FWD_STEP_BODY(5, false);
#pragma unroll
      for (int kk = 0; kk < 6; ++kk) emit += em[kk];
#pragma unroll
      for (int kk = 1; kk < 6; ++kk) trn += tr[kk];  // t==0: no transition
    } else {
      BWD_STEP_BODY(0, false);
      BWD_STEP_BODY(1, false);
      BWD_STEP_BODY(2, false);
      BWD_STEP_BODY(3, false);
      BWD_STEP_BODY(4, false);
      BWD_STEP_BODY(5, false);
#pragma unroll
      for (int kk = 0; kk < 6; ++kk) { emit += em[kk]; trn += tr[kk]; }
    }
    pcur = pc6[SPB - 1];
#pragma unroll
    for (int kk = 0; kk < SPB; ++kk) pc6[kk] = pn6[kk];
  }

  // ================= windows 1..20 (branch-free bodies) =================
#pragma unroll 1
  for (int b = 1; b <= 20; ++b) {
    const int tb = b * SPB;
    WAITV0;                   // window b staged
    PREFETCH_WIN(b + 1)
    const float* lxq = &lx[b & 1][q * XSTRIDE];
    float e[SPB * 3];
    EBATCH(0, 5)
    float em[SPB], tr[SPB];
    int pn6[SPB];
    if (fwd) { EMTR_FWD(6) } else { EMTR_BWD(6) }
    PREREAD_PN(tb + SPB)
    if (fwd) {
      FWD_STEP_BODY(0, true);   // rescale once per window
      FWD_STEP_BODY(1, false);
      FWD_STEP_BODY(2, false);
      FWD_STEP_BODY(3, false);
      FWD_STEP_BODY(4, false);
      FWD_STEP_BODY(5, false);
    } else {
      BWD_STEP_BODY(0, true);
      BWD_STEP_BODY(1, false);
      BWD_STEP_BODY(2, false);
      BWD_STEP_BODY(3, false);
      BWD_STEP_BODY(4, false);
      BWD_STEP_BODY(5, false);
    }
#pragma unroll
    for (int kk = 0; kk < 6; ++kk) { emit += em[kk]; trn += tr[kk]; }
    pcur = pc6[SPB - 1];
#pragma unroll
    for (int kk = 0; kk < SPB; ++kk) pc6[kk] = pn6[kk];
  }

  // ================= tail window 21 (2 steps: t=126,127) =================
  {
    WAITV0;                   // window 21 staged
    const float* lxq = &lx[1][q * XSTRIDE];   // 21 & 1
    float e[SPB * 3];
    float em[SPB], tr[SPB];
    if (fwd) {
      EBATCH(0, 1)            // tt=0,1 -> t=126,127
      EMTR_FWD(2)
      FWD_STEP_BODY(0, true);
      FWD_STEP_BODY(1, false);
    } else {
      EBATCH(4, 5)            // tt=5,4 -> t=129,128
      EMTR_BWD(2)
      BWD_STEP_BODY(0, true);
      BWD_STEP_BODY(1, false);
    }
#pragma unroll
    for (int kk = 0; kk < 2; ++kk) { emit += em[kk]; trn += tr[kk]; }
  }

  // ---- write partials (field-major)
  const int sq = seq0 + q;
  float* wp = ws + sq;
  if (fwd) {
    if (c < 3) {
#pragma unroll
      for (int k = 0; k < 3; ++k) wp[(3 * c + k) * B_N] = o[k];
    } else {
      wp[9 * B_N] = (float)ce;
      wp[10 * B_N] = emit + trn + initv[plr[0]];
    }
  } else {
    if (c < 3) {
#pragma unroll
      for (int k = 0; k < 3; ++k) wp[(11 + 3 * c + k) * B_N] = o[k];
    } else {
      wp[20 * B_N] = (float)ce;
      wp[21 * B_N] = emit + trn;
    }
  }
}

__global__ __launch_bounds__(256) void crf_combine(
    const float* __restrict__ ws, float* __restrict__ out)
{
  const int s = blockIdx.x * 256 + threadIdx.x;
  float dot = 0.f;
#pragma unroll
  for (int i = 0; i < 9; ++i)
    dot = fmaf(ws[i * B_N + s], ws[(11 + i) * B_N + s], dot);
  const float score =
      (__builtin_amdgcn_logf(dot) + ws[9 * B_N + s] + ws[20 * B_N + s]) * LN2f;
  out[s] = score - (ws[10 * B_N + s] + ws[21 * B_N + s]);
}

extern "C" void kernel_launch(void* const* d_in, const int* in_sizes, int n_in,
                              void* d_out, int out_size, void* d_ws, size_t ws_size,
                              hipStream_t stream) {
  (void)in_sizes; (void)n_in; (void)out_size; (void)ws_size;
  const float* xg    = (const float*)d_in[0];
  const int*   path  = (const int*)d_in[1];
  const float* tran  = (const float*)d_in[2];
  const float* initv = (const float*)d_in[3];
  float* ws  = (float*)d_ws;    // 22*8192*4 = 721 KB
  float* out = (float*)d_out;

  crf_half<<<2 * NDIR_BLOCKS, 64, 0, stream>>>(xg, path, tran, initv, ws);
  crf_combine<<<B_N / 256, 256, 0, stream>>>(ws, out);
}